// Round 5
// baseline (111.162 us; speedup 1.0000x reference)
//
#include <hip/hip_runtime.h>

// repeatPast top-k branch:
//   wh = cumsum(history, axis=1)  [B,S,L]; keep wh where label in top-k per (b,s)
//   (ties -> smaller label), else 0.  B=64, S=64, L=8192, k=30 (runtime).
//
// Two kernels:
//  A) cumsum_full4: thread per 4 adjacent labels (float4). One dwordx4 load +
//     4 adds + one dwordx4 store per s-step, fully unrolled (64 steps) so loads
//     pipeline ahead of the dependent accumulate chain. 16B/lane = coalescing
//     sweet spot; 1KB/wave contiguous chunks.
//  B) select_row: ONE BLOCK PER (b,s) ROW (4096 independent blocks). Reads its
//     row from d_out (L3-warm), selects top-k exactly (analytic threshold probe
//     + bisection fallback + exact-duplicate stall path), writes the masked row
//     back in place. Unchanged (validated, ~34 us, ~7.9 TB/s effective).

constexpr int B_ = 64, S_ = 64, L_ = 8192;
constexpr int THREADS = 256;
constexpr int VPT = L_ / THREADS;      // 32 values per thread (kernel B)
constexpr int CAND_MAX = 160;

__device__ const float ZTAB[16] = {
    0.0f, 1.70f, 2.14f, 2.27f, 2.32f, 2.34f, 2.35f, 2.36f,
    2.37f, 2.375f, 2.38f, 2.385f, 2.39f, 2.39f, 2.395f, 2.395f};

__global__ __launch_bounds__(THREADS)
void cumsum_full4(const float* __restrict__ in, float* __restrict__ out)
{
    int t = blockIdx.x * THREADS + threadIdx.x;   // t = b*2048 + l4
    int b = t >> 11;
    int l4 = t & 2047;
    const float4* p = (const float4*)(in + ((size_t)b << 19)) + l4;
    float4* o = (float4*)(out + ((size_t)b << 19)) + l4;

    float4 a = make_float4(0.f, 0.f, 0.f, 0.f);
#pragma unroll
    for (int s = 0; s < S_; ++s) {
        float4 v = p[(size_t)s << 11];            // stride L_/4 float4s per row
        a.x += v.x; a.y += v.y; a.z += v.z; a.w += v.w;
        o[(size_t)s << 11] = a;
    }
}

__global__ __launch_bounds__(THREADS)
void select_row(const int* __restrict__ topk_p, float* __restrict__ out)
{
    __shared__ int wtot[4];
    __shared__ unsigned candv[CAND_MAX];
    __shared__ unsigned short candi[CAND_MAX];
    __shared__ int s_cnt;
    __shared__ unsigned s_Tb;
    __shared__ int s_aux;

    const int tid = threadIdx.x;
    const int lane = tid & 63;
    const int wv = tid >> 6;
    const int blk = blockIdx.x;       // b*64 + s
    const int s = blk & (S_ - 1);
    const int k = *topk_p;

    float* row = out + (size_t)blk * L_ + tid * VPT;

    float acc[VPT];
    {
        const float4* rp = (const float4*)row;
#pragma unroll
        for (int q = 0; q < VPT / 4; ++q) {
            float4 v = rp[q];
            acc[4*q+0] = v.x; acc[4*q+1] = v.y; acc[4*q+2] = v.z; acc[4*q+3] = v.w;
        }
    }

    // ---------- find selection rule for k-th largest (exact) ----------
    const int n = s + 1;
    const float mu = 0.5f * (float)n;
    const float sig = sqrtf((float)n * (1.0f / 12.0f));
    const float z = (n < 16) ? ZTAB[n] : 2.40f;

    unsigned lo = 0u;                        // invariant: count(>=lo) >= k
    unsigned hi = __float_as_uint((float)n); // sum of n uniforms < n => count(>=hi)==0
    int hiC = 0;
    unsigned T = __float_as_uint(mu + z * sig);
    if (!(T > lo && T < hi)) T = lo + ((hi - lo) >> 1);

    unsigned Tsel = 0;
    int path = 0;        // 0: candidate rank-select; 1: duplicate stall path
    int needEq = 0;

    for (int it = 0; it < 40; ++it) {
        int cnt = 0;
#pragma unroll
        for (int j = 0; j < VPT; ++j)
            cnt += (__float_as_uint(acc[j]) >= T) ? 1 : 0;
#pragma unroll
        for (int off = 32; off >= 1; off >>= 1) cnt += __shfl_xor(cnt, off, 64);
        if (it != 0) __syncthreads();       // WAR on wtot across iterations
        if (lane == 0) wtot[wv] = cnt;
        if (tid == 0) s_cnt = 0;
        __syncthreads();
        const int ctot = wtot[0] + wtot[1] + wtot[2] + wtot[3];

        if (ctot >= k && ctot <= CAND_MAX) { Tsel = T; path = 0; break; }
        if (ctot >= k) { lo = T; } else { hi = T; hiC = ctot; }
        if (hi - lo <= 1u) { Tsel = lo; path = 1; needEq = k - hiC; break; }
        T = lo + ((hi - lo) >> 1);
    }

    unsigned Tb;
    int idxT = 0, excl = 0;

    if (path == 0) {
#pragma unroll
        for (int j = 0; j < VPT; ++j) {
            unsigned u = __float_as_uint(acc[j]);
            if (u >= Tsel) {
                int p = atomicAdd(&s_cnt, 1);
                if (p < CAND_MAX) {
                    candv[p] = u;
                    candi[p] = (unsigned short)(tid * VPT + j);
                }
            }
        }
        __syncthreads();
        const int cc = s_cnt;
        if (tid < cc) {
            unsigned mv = candv[tid];
            int mi = candi[tid];
            int rk = 0;
            for (int j2 = 0; j2 < cc; ++j2) {
                unsigned ov = candv[j2];
                int oi = candi[j2];
                rk += ((ov > mv) || (ov == mv && oi < mi)) ? 1 : 0;
            }
            if (rk == k - 1) { s_Tb = mv; s_aux = mi; }
        }
        __syncthreads();
        Tb = s_Tb;
        idxT = s_aux;
    } else {
        // k-th value == Tsel with many exact duplicates: include all > Tsel
        // plus the first needEq duplicates in label (thread-major) order.
        int myeq = 0;
#pragma unroll
        for (int j = 0; j < VPT; ++j)
            myeq += (__float_as_uint(acc[j]) == Tsel) ? 1 : 0;
        int sc = myeq;
#pragma unroll
        for (int off = 1; off < 64; off <<= 1) {
            int o = __shfl_up(sc, off, 64);
            if (lane >= off) sc += o;
        }
        __syncthreads();
        if (lane == 63) wtot[wv] = sc;
        __syncthreads();
        excl = sc - myeq;
        for (int w2 = 0; w2 < wv; ++w2) excl += wtot[w2];
        Tb = Tsel;
    }

    // ---------- masked write (in place) ----------
    float4* ow = (float4*)row;
    int run = excl;
#pragma unroll
    for (int q = 0; q < VPT / 4; ++q) {
        float res[4];
#pragma unroll
        for (int m = 0; m < 4; ++m) {
            const int j = 4 * q + m;
            const unsigned u = __float_as_uint(acc[j]);
            bool inc;
            if (path == 0) {
                inc = (u > Tb) || (u == Tb && (tid * VPT + j) <= idxT);
            } else {
                if (u > Tb) inc = true;
                else if (u == Tb) { inc = (run < needEq); ++run; }
                else inc = false;
            }
            res[m] = inc ? acc[j] : 0.f;
        }
        float4 o4; o4.x = res[0]; o4.y = res[1]; o4.z = res[2]; o4.w = res[3];
        ow[q] = o4;
    }
}

extern "C" void kernel_launch(void* const* d_in, const int* in_sizes, int n_in,
                              void* d_out, int out_size, void* d_ws, size_t ws_size,
                              hipStream_t stream) {
    const float* hist_in = (const float*)d_in[0];
    const int* topk = (const int*)d_in[1];
    float* out = (float*)d_out;

    hipLaunchKernelGGL(cumsum_full4, dim3((B_ * L_ / 4) / THREADS), dim3(THREADS),
                       0, stream, hist_in, out);
    hipLaunchKernelGGL(select_row, dim3(B_ * S_), dim3(THREADS),
                       0, stream, topk, out);
}

// Round 6
// 108.990 us; speedup vs baseline: 1.0199x; 1.0199x over previous
//
#include <hip/hip_runtime.h>

// repeatPast top-k branch:
//   wh = cumsum(history, axis=1)  [B,S,L]; keep wh where label in top-k per (b,s)
//   (ties -> smaller label), else 0.  B=64, S=64, L=8192, k=30 (runtime).
//
// Two kernels:
//  A) cumsum_pipe: thread per 4 adjacent labels (float4), walking s with an
//     explicit prefetch-distance-8 rolling register buffer -> 8 independent
//     loads in flight per wave (R3-R5 all showed MLP=1, ~800 GB/s, latency-
//     bound at ~900cy/iter; this amortizes HBM latency 8x).
//  B) select_row: ONE BLOCK PER (b,s) ROW (4096 independent blocks). Reads its
//     row from d_out (L3-warm), selects top-k exactly (analytic threshold probe
//     + bisection fallback + exact-duplicate stall path), writes the masked row
//     back in place. Unchanged (validated, ~34 us).

constexpr int B_ = 64, S_ = 64, L_ = 8192;
constexpr int THREADS = 256;
constexpr int VPT = L_ / THREADS;      // 32 values per thread (kernel B)
constexpr int CAND_MAX = 160;

__device__ const float ZTAB[16] = {
    0.0f, 1.70f, 2.14f, 2.27f, 2.32f, 2.34f, 2.35f, 2.36f,
    2.37f, 2.375f, 2.38f, 2.385f, 2.39f, 2.39f, 2.395f, 2.395f};

__global__ __launch_bounds__(THREADS)
void cumsum_pipe(const float* __restrict__ in, float* __restrict__ out)
{
    int t = blockIdx.x * THREADS + threadIdx.x;   // t = b*2048 + l4
    int b = t >> 11;
    int l4 = t & 2047;
    const float4* p = (const float4*)(in + ((size_t)b << 19)) + l4;
    float4* o = (float4*)(out + ((size_t)b << 19)) + l4;

    constexpr int D = 8;                          // prefetch distance
    float4 buf[D];
#pragma unroll
    for (int j = 0; j < D; ++j)
        buf[j] = p[(size_t)j << 11];              // 8 loads in flight

    float4 a = make_float4(0.f, 0.f, 0.f, 0.f);
#pragma unroll
    for (int s = 0; s < S_; ++s) {
        float4 v = buf[s & (D - 1)];              // wait only for load issued 8 iters ago
        if (s + D < S_)
            buf[s & (D - 1)] = p[(size_t)(s + D) << 11];  // re-issue immediately
        a.x += v.x; a.y += v.y; a.z += v.z; a.w += v.w;
        o[(size_t)s << 11] = a;
    }
}

__global__ __launch_bounds__(THREADS)
void select_row(const int* __restrict__ topk_p, float* __restrict__ out)
{
    __shared__ int wtot[4];
    __shared__ unsigned candv[CAND_MAX];
    __shared__ unsigned short candi[CAND_MAX];
    __shared__ int s_cnt;
    __shared__ unsigned s_Tb;
    __shared__ int s_aux;

    const int tid = threadIdx.x;
    const int lane = tid & 63;
    const int wv = tid >> 6;
    const int blk = blockIdx.x;       // b*64 + s
    const int s = blk & (S_ - 1);
    const int k = *topk_p;

    float* row = out + (size_t)blk * L_ + tid * VPT;

    float acc[VPT];
    {
        const float4* rp = (const float4*)row;
#pragma unroll
        for (int q = 0; q < VPT / 4; ++q) {
            float4 v = rp[q];
            acc[4*q+0] = v.x; acc[4*q+1] = v.y; acc[4*q+2] = v.z; acc[4*q+3] = v.w;
        }
    }

    // ---------- find selection rule for k-th largest (exact) ----------
    const int n = s + 1;
    const float mu = 0.5f * (float)n;
    const float sig = sqrtf((float)n * (1.0f / 12.0f));
    const float z = (n < 16) ? ZTAB[n] : 2.40f;

    unsigned lo = 0u;                        // invariant: count(>=lo) >= k
    unsigned hi = __float_as_uint((float)n); // sum of n uniforms < n => count(>=hi)==0
    int hiC = 0;
    unsigned T = __float_as_uint(mu + z * sig);
    if (!(T > lo && T < hi)) T = lo + ((hi - lo) >> 1);

    unsigned Tsel = 0;
    int path = 0;        // 0: candidate rank-select; 1: duplicate stall path
    int needEq = 0;

    for (int it = 0; it < 40; ++it) {
        int cnt = 0;
#pragma unroll
        for (int j = 0; j < VPT; ++j)
            cnt += (__float_as_uint(acc[j]) >= T) ? 1 : 0;
#pragma unroll
        for (int off = 32; off >= 1; off >>= 1) cnt += __shfl_xor(cnt, off, 64);
        if (it != 0) __syncthreads();       // WAR on wtot across iterations
        if (lane == 0) wtot[wv] = cnt;
        if (tid == 0) s_cnt = 0;
        __syncthreads();
        const int ctot = wtot[0] + wtot[1] + wtot[2] + wtot[3];

        if (ctot >= k && ctot <= CAND_MAX) { Tsel = T; path = 0; break; }
        if (ctot >= k) { lo = T; } else { hi = T; hiC = ctot; }
        if (hi - lo <= 1u) { Tsel = lo; path = 1; needEq = k - hiC; break; }
        T = lo + ((hi - lo) >> 1);
    }

    unsigned Tb;
    int idxT = 0, excl = 0;

    if (path == 0) {
#pragma unroll
        for (int j = 0; j < VPT; ++j) {
            unsigned u = __float_as_uint(acc[j]);
            if (u >= Tsel) {
                int p = atomicAdd(&s_cnt, 1);
                if (p < CAND_MAX) {
                    candv[p] = u;
                    candi[p] = (unsigned short)(tid * VPT + j);
                }
            }
        }
        __syncthreads();
        const int cc = s_cnt;
        if (tid < cc) {
            unsigned mv = candv[tid];
            int mi = candi[tid];
            int rk = 0;
            for (int j2 = 0; j2 < cc; ++j2) {
                unsigned ov = candv[j2];
                int oi = candi[j2];
                rk += ((ov > mv) || (ov == mv && oi < mi)) ? 1 : 0;
            }
            if (rk == k - 1) { s_Tb = mv; s_aux = mi; }
        }
        __syncthreads();
        Tb = s_Tb;
        idxT = s_aux;
    } else {
        // k-th value == Tsel with many exact duplicates: include all > Tsel
        // plus the first needEq duplicates in label (thread-major) order.
        int myeq = 0;
#pragma unroll
        for (int j = 0; j < VPT; ++j)
            myeq += (__float_as_uint(acc[j]) == Tsel) ? 1 : 0;
        int sc = myeq;
#pragma unroll
        for (int off = 1; off < 64; off <<= 1) {
            int o = __shfl_up(sc, off, 64);
            if (lane >= off) sc += o;
        }
        __syncthreads();
        if (lane == 63) wtot[wv] = sc;
        __syncthreads();
        excl = sc - myeq;
        for (int w2 = 0; w2 < wv; ++w2) excl += wtot[w2];
        Tb = Tsel;
    }

    // ---------- masked write (in place) ----------
    float4* ow = (float4*)row;
    int run = excl;
#pragma unroll
    for (int q = 0; q < VPT / 4; ++q) {
        float res[4];
#pragma unroll
        for (int m = 0; m < 4; ++m) {
            const int j = 4 * q + m;
            const unsigned u = __float_as_uint(acc[j]);
            bool inc;
            if (path == 0) {
                inc = (u > Tb) || (u == Tb && (tid * VPT + j) <= idxT);
            } else {
                if (u > Tb) inc = true;
                else if (u == Tb) { inc = (run < needEq); ++run; }
                else inc = false;
            }
            res[m] = inc ? acc[j] : 0.f;
        }
        float4 o4; o4.x = res[0]; o4.y = res[1]; o4.z = res[2]; o4.w = res[3];
        ow[q] = o4;
    }
}

extern "C" void kernel_launch(void* const* d_in, const int* in_sizes, int n_in,
                              void* d_out, int out_size, void* d_ws, size_t ws_size,
                              hipStream_t stream) {
    const float* hist_in = (const float*)d_in[0];
    const int* topk = (const int*)d_in[1];
    float* out = (float*)d_out;

    hipLaunchKernelGGL(cumsum_pipe, dim3((B_ * L_ / 4) / THREADS), dim3(THREADS),
                       0, stream, hist_in, out);
    hipLaunchKernelGGL(select_row, dim3(B_ * S_), dim3(THREADS),
                       0, stream, topk, out);
}